// Round 3
// baseline (2856.310 us; speedup 1.0000x reference)
//
#include <hip/hip_runtime.h>

// ---- problem dims ----
#define B_ 120
#define T_ 20
#define L_ 144
#define D_ 64
#define H_ 1024
#define A_ 256
#define R_ 9216   // L*D
#define G_ 4096   // 4H

typedef unsigned short u16;
typedef unsigned int   u32;
typedef __bf16 bf16x8 __attribute__((ext_vector_type(8)));
typedef float  f32x4  __attribute__((ext_vector_type(4)));

// d_out element offsets (f32 elements)
#define OUT_VIS 0
#define OUT_HDD 22118400     // 2400*9216
#define OUT_ALP 24576000     // + 2400*1024
#define OUT_BET 24921600     // + 2400*144

// ws byte offsets
#define WS_C     0            // 120*1024 f32
#define WS_HBF   491520       // 120*1024 bf16
#define WS_VBF   737280       // 120*9216 bf16 (current-step v)
#define WS_WXAT  2949120      // 256*64 bf16
#define WS_WHAT  2981888      // 256*1024 bf16
#define WS_WBT   3506176      // 64*1024 bf16
#define WS_GATES 3637248      // 120*4096 f32
#define WS_WIHBF 5603328      // 4096*9216 bf16 (big path only)
#define WS_WHHBF 81100800     // 4096*1024 bf16 (big path only)
#define WS_BIG_NEED 89489408ull

__device__ inline u16 f2b(float f){ union{float f; u32 i;} v; v.f = f;
  return (u16)((v.i + 0x7FFFu + ((v.i>>16)&1u)) >> 16); }
__device__ inline float sigf(float x){ return 1.0f/(1.0f+__expf(-x)); }
__device__ inline float tanh_fast(float x){ return 1.0f - 2.0f/(__expf(2.0f*x)+1.0f); }

// pack 8 f32 -> 8 bf16 (RNE) and store 16B
__device__ inline void store8(u16* dst, const float* src){
  float4 x = *(const float4*)src, y = *(const float4*)(src+4);
  uint4 o;
  o.x = (u32)f2b(x.x) | ((u32)f2b(x.y)<<16);
  o.y = (u32)f2b(x.z) | ((u32)f2b(x.w)<<16);
  o.z = (u32)f2b(y.x) | ((u32)f2b(y.y)<<16);
  o.w = (u32)f2b(y.z) | ((u32)f2b(y.w)<<16);
  *(uint4*)dst = o;
}
// load 8 f32 -> bf16x8 frag
__device__ inline bf16x8 cvt8(const float* src){
  float4 x = *(const float4*)src, y = *(const float4*)(src+4);
  union{ bf16x8 v; u16 s[8]; } u;
  u.s[0]=f2b(x.x); u.s[1]=f2b(x.y); u.s[2]=f2b(x.z); u.s[3]=f2b(x.w);
  u.s[4]=f2b(y.x); u.s[5]=f2b(y.y); u.s[6]=f2b(y.z); u.s[7]=f2b(y.w);
  return u.v;
}

// ---------------------------------------------------------------------------
// k_pre: blocks 0..255 whaT rows; 256..319 wbT rows; 320 wxaT. f32 -> bf16.
// ---------------------------------------------------------------------------
__global__ __launch_bounds__(256) void k_pre(
    const float* __restrict__ Wxa, const float* __restrict__ Wha, const float* __restrict__ Wb,
    u16* __restrict__ wxaT, u16* __restrict__ whaT, u16* __restrict__ wbT){
  int bx = blockIdx.x, tid = threadIdx.x;
  if(bx < 256){
    int a = bx;
    for(int k = tid; k < H_; k += 256) whaT[a*H_ + k] = f2b(Wha[k*A_ + a]);
  } else if(bx < 320){
    int d = bx - 256;
    for(int k = tid; k < H_; k += 256) wbT[d*H_ + k] = f2b(Wb[k*D_ + d]);
  } else {
    int a = tid;
    for(int k = 0; k < 64; k++) wxaT[a*64 + k] = f2b(Wxa[k*A_ + a]);
  }
}

// ---------------------------------------------------------------------------
// k_conv (big path): W_ih, W_hh f32 -> bf16 in ws.
// ---------------------------------------------------------------------------
__global__ __launch_bounds__(256) void k_conv(
    const float* __restrict__ Wih, const float* __restrict__ Whh,
    u16* __restrict__ wihbf, u16* __restrict__ whhbf){
  const size_t NIH8 = (size_t)G_*R_/8, NHH8 = (size_t)G_*H_/8, TOT = NIH8+NHH8;
  for(size_t i = (size_t)blockIdx.x*256 + threadIdx.x; i < TOT; i += (size_t)gridDim.x*256){
    if(i < NIH8) store8(wihbf + i*8, Wih + i*8);
    else         store8(whhbf + (i-NIH8)*8, Whh + (i-NIH8)*8);
  }
}

// ---------------------------------------------------------------------------
// k_init: 120 blocks. f0 = mean_L feat[b,0]; h0 -> hbf (bf16), c0 -> c (f32).
// ---------------------------------------------------------------------------
__global__ __launch_bounds__(256) void k_init(
    const float* __restrict__ feat, const float* __restrict__ Whw, const float* __restrict__ Whb,
    const float* __restrict__ Wcw, const float* __restrict__ Wcb,
    float* __restrict__ c, u16* __restrict__ hbf){
  int b = blockIdx.x, tid = threadIdx.x;
  __shared__ float fp[4][64];
  __shared__ float f0[64];
  int d = tid & 63, g = tid >> 6;
  const float* xt = feat + (size_t)(b*T_)*R_;
  float acc = 0.f;
  for(int l = g; l < L_; l += 4) acc += xt[l*64 + d];
  fp[g][d] = acc;
  __syncthreads();
  if(tid < 64) f0[tid] = (fp[0][tid]+fp[1][tid]+fp[2][tid]+fp[3][tid]) * (1.0f/L_);
  __syncthreads();
  for(int jj=0; jj<4; jj++){
    int j = tid + jj*256;
    float ah=0.f, ac2=0.f;
    for(int dd=0; dd<64; dd++){
      float fv = f0[dd];
      ah  += fv * Whw[j*64+dd];
      ac2 += fv * Wcw[j*64+dd];
    }
    hbf[b*H_ + j] = f2b(tanh_fast(ah + Whb[j]));
    c[b*H_ + j]   = tanh_fast(ac2 + Wcb[j]);
  }
}

// ---------------------------------------------------------------------------
// k_att: one block per b (120 x 256).
//  0) zero gates[b]
//  1) ha = h@Wha, beta = sig(h@Wb+bb) via broadcast-A MFMA (K=1024, from hbf)
//  2) scores via MFMA xt@wxaT^T -> tanh(.+ha)*wa, 16-lane reduce -> spart
//  3) softmax over L=144 -> alpha (f32 out) ; 4) v = xt*(1+alpha)*beta
//     -> vis (f32 out) + vbf (bf16 ws, GEMM A-operand)
// ---------------------------------------------------------------------------
__global__ __launch_bounds__(256) void k_att(
    const float* __restrict__ feat, const u16* __restrict__ wxaT, const u16* __restrict__ whaT,
    const u16* __restrict__ wbT, const float* __restrict__ wa, const float* __restrict__ bb,
    const u16* __restrict__ hbf, float* __restrict__ gates, u16* __restrict__ vbf,
    float* __restrict__ out, int t){
  int b = blockIdx.x, tid = threadIdx.x;
  int lane = tid & 63, w = tid >> 6, r = lane & 15, q = lane >> 4;
  size_t row = (size_t)b*T_ + t;

  float* gb = gates + (size_t)b*G_;
  for(int i = tid; i < G_; i += 256) gb[i] = 0.f;

  __shared__ float hasm[256];
  __shared__ float wasm[256];
  __shared__ float bsm[64];
  __shared__ float spart[4][160];
  __shared__ float amul[160];

  wasm[tid] = wa[tid];

  // ---- phase 1: ha (256 cols) + beta logits (64 cols), K=1024 ----
  {
    const u16* hb = hbf + b*H_;
    f32x4 pacc[5];
    #pragma unroll
    for(int ni=0; ni<5; ni++) pacc[ni] = (f32x4){0.f,0.f,0.f,0.f};
    for(int k0 = 0; k0 < H_; k0 += 32){
      bf16x8 afr = *(const bf16x8*)(hb + k0 + q*8);   // broadcast: all 16 A-rows = h
      #pragma unroll
      for(int ni=0; ni<4; ni++){
        bf16x8 bfr = *(const bf16x8*)(whaT + (size_t)(w*64 + ni*16 + r)*H_ + k0 + q*8);
        pacc[ni] = __builtin_amdgcn_mfma_f32_16x16x32_bf16(afr, bfr, pacc[ni], 0,0,0);
      }
      bf16x8 bfr = *(const bf16x8*)(wbT + (size_t)(w*16 + r)*H_ + k0 + q*8);
      pacc[4] = __builtin_amdgcn_mfma_f32_16x16x32_bf16(afr, bfr, pacc[4], 0,0,0);
    }
    if(q == 0){  // all C rows identical (A rows identical); col = lane&15 = r
      #pragma unroll
      for(int ni=0; ni<4; ni++) hasm[w*64 + ni*16 + r] = pacc[ni][0];
      float bv = sigf(pacc[4][0] + bb[w*16 + r]);
      bsm[w*16 + r] = bv;
      out[OUT_BET + row*D_ + w*16 + r] = bv;
    }
  }
  __syncthreads();

  // ---- phase 2: s[l] = sum_a tanh(xa[l,a]+ha[a])*wa[a] ----
  const float* xt = feat + row*R_;
  {
    bf16x8 xb[4][2];
    #pragma unroll
    for(int ni=0; ni<4; ni++){
      int n = w*64 + ni*16 + r;
      xb[ni][0] = *(const bf16x8*)(wxaT + n*64 +  0 + q*8);
      xb[ni][1] = *(const bf16x8*)(wxaT + n*64 + 32 + q*8);
    }
    for(int m=0; m<9; m++){
      bf16x8 a0 = cvt8(xt + (m*16 + r)*64 +  0 + q*8);
      bf16x8 a1 = cvt8(xt + (m*16 + r)*64 + 32 + q*8);
      float ps0=0.f, ps1=0.f, ps2=0.f, ps3=0.f;
      #pragma unroll
      for(int ni=0; ni<4; ni++){
        f32x4 acc = (f32x4){0.f,0.f,0.f,0.f};
        acc = __builtin_amdgcn_mfma_f32_16x16x32_bf16(a0, xb[ni][0], acc, 0,0,0);
        acc = __builtin_amdgcn_mfma_f32_16x16x32_bf16(a1, xb[ni][1], acc, 0,0,0);
        int col = w*64 + ni*16 + r;
        float ha = hasm[col], wv = wasm[col];
        ps0 += tanh_fast(acc[0] + ha) * wv;
        ps1 += tanh_fast(acc[1] + ha) * wv;
        ps2 += tanh_fast(acc[2] + ha) * wv;
        ps3 += tanh_fast(acc[3] + ha) * wv;
      }
      float ps[4] = {ps0, ps1, ps2, ps3};
      #pragma unroll
      for(int reg=0; reg<4; reg++){
        float v = ps[reg];
        v += __shfl_xor(v, 1); v += __shfl_xor(v, 2);
        v += __shfl_xor(v, 4); v += __shfl_xor(v, 8);
        if(r == 0) spart[w][m*16 + q*4 + reg] = v;   // (l, summed over 16 a-cols)
      }
    }
  }
  __syncthreads();

  // ---- phase 3: softmax over L=144 (wave 0) ----
  if(tid < 64){
    float v0 = spart[0][tid]    + spart[1][tid]    + spart[2][tid]    + spart[3][tid];
    float v1 = spart[0][tid+64] + spart[1][tid+64] + spart[2][tid+64] + spart[3][tid+64];
    float v2 = -1e30f;
    if(tid < 16)
      v2 = spart[0][tid+128] + spart[1][tid+128] + spart[2][tid+128] + spart[3][tid+128];
    float m = fmaxf(fmaxf(v0, v1), v2);
    #pragma unroll
    for(int off=32; off; off>>=1) m = fmaxf(m, __shfl_xor(m, off));
    float e0 = __expf(v0-m), e1 = __expf(v1-m);
    float e2 = (tid < 16) ? __expf(v2-m) : 0.0f;
    float s = (e0+e1)+e2;
    #pragma unroll
    for(int off=32; off; off>>=1) s += __shfl_xor(s, off);
    float inv = 1.0f/s;
    float al0 = e0*inv, al1 = e1*inv;
    amul[tid] = 1.0f+al0; amul[tid+64] = 1.0f+al1;
    out[OUT_ALP + row*L_ + tid]    = al0;
    out[OUT_ALP + row*L_ + tid+64] = al1;
    if(tid < 16){
      float al2 = e2*inv;
      amul[tid+128] = 1.0f+al2;
      out[OUT_ALP + row*L_ + tid+128] = al2;
    }
  }
  __syncthreads();

  // ---- phase 4: v = xt*(1+alpha)*beta -> vis f32 + vbf bf16 ----
  float* vout = out + OUT_VIS + row*R_;
  u16* vb = vbf + (size_t)b*R_;
  for(int i = tid; i < R_/2; i += 256){
    int e = i*2;
    int l = e >> 6, d = e & 63;
    float2 x = *(const float2*)(xt + e);
    float m1 = amul[l];
    float r0 = x.x * m1 * bsm[d];
    float r1 = x.y * m1 * bsm[d+1];
    float2 o2 = {r0, r1};
    *(float2*)(vout + e) = o2;
    *(u32*)(vb + e) = (u32)f2b(r0) | ((u32)f2b(r1) << 16);
  }
}

// ---------------------------------------------------------------------------
// k_gemm<BF>: split-K; s=0..5: v@Wih^T (K=1536), s=6: h@Whh^T (K=1024).
// A from vbf/hbf (bf16). B from converted bf16 ws (BF) or f32 inputs (!BF).
// atomicAdd f32 into gates. grid 448 = 7 x 64 n-tiles; 128 thr; 128M x 64N.
// ---------------------------------------------------------------------------
template<bool BF>
__global__ __launch_bounds__(128) void k_gemm(
    const u16* __restrict__ vbf, const u16* __restrict__ hbf,
    const void* __restrict__ Wih_, const void* __restrict__ Whh_,
    float* __restrict__ gates){
  int bx = blockIdx.x;
  int s  = bx >> 6;
  int j0 = (bx & 63) * 64;
  int tid = threadIdx.x;
  const int Ks = (s==6) ? 1024 : 1536;
  __shared__ u16 a_lds[128*72];   // stride 72 (+8 pad)
  __shared__ u16 b_lds[64*72];
  int lane = tid & 63, w = tid >> 6;
  int r = lane & 15, q = lane >> 4;
  f32x4 acc[4][4];
  #pragma unroll
  for(int i=0;i<4;i++)
    #pragma unroll
    for(int j=0;j<4;j++) acc[i][j] = (f32x4){0.f,0.f,0.f,0.f};

  for(int k0 = 0; k0 < Ks; k0 += 64){
    __syncthreads();
    #pragma unroll
    for(int i=0;i<8;i++){                 // A: 128 rows x 8 chunks (16B bf16)
      int idx = tid + i*128;
      int rw = idx >> 3, cch = idx & 7;
      float4 val = {0.f,0.f,0.f,0.f};
      if(rw < B_){
        const u16* src = (s==6) ? (hbf + (size_t)rw*H_ + k0 + cch*8)
                                : (vbf + (size_t)rw*R_ + s*1536 + k0 + cch*8);
        val = *(const float4*)src;
      }
      *(float4*)&a_lds[rw*72 + cch*8] = val;
    }
    #pragma unroll
    for(int i=0;i<4;i++){                 // B: 64 rows x 8 chunks
      int idx = tid + i*128;
      int rw = idx >> 3, cch = idx & 7;
      if(BF){
        const u16* src = (s==6) ? ((const u16*)Whh_ + (size_t)(j0+rw)*H_ + k0 + cch*8)
                                : ((const u16*)Wih_ + (size_t)(j0+rw)*R_ + s*1536 + k0 + cch*8);
        *(float4*)&b_lds[rw*72 + cch*8] = *(const float4*)src;
      } else {
        const float* src = (s==6) ? ((const float*)Whh_ + (size_t)(j0+rw)*H_ + k0 + cch*8)
                                  : ((const float*)Wih_ + (size_t)(j0+rw)*R_ + s*1536 + k0 + cch*8);
        store8(&b_lds[rw*72 + cch*8], src);
      }
    }
    __syncthreads();
    #pragma unroll
    for(int kb=0; kb<2; kb++){
      bf16x8 af[4], bfr[4];
      #pragma unroll
      for(int mi=0; mi<4; mi++) af[mi]  = *(const bf16x8*)&a_lds[(w*64+mi*16+r)*72 + kb*32 + q*8];
      #pragma unroll
      for(int ni=0; ni<4; ni++) bfr[ni] = *(const bf16x8*)&b_lds[(ni*16+r)*72 + kb*32 + q*8];
      #pragma unroll
      for(int mi=0; mi<4; mi++)
        #pragma unroll
        for(int ni=0; ni<4; ni++)
          acc[mi][ni] = __builtin_amdgcn_mfma_f32_16x16x32_bf16(af[mi], bfr[ni], acc[mi][ni], 0,0,0);
    }
  }
  #pragma unroll
  for(int mi=0; mi<4; mi++)
    #pragma unroll
    for(int ni=0; ni<4; ni++)
      #pragma unroll
      for(int reg=0; reg<4; reg++){
        int m = w*64 + mi*16 + q*4 + reg;
        if(m < B_) atomicAdd(&gates[(size_t)m*G_ + j0 + ni*16 + r], acc[mi][ni][reg]);
      }
}

// ---------------------------------------------------------------------------
// k_lstm: 480 blocks x 256 — pointwise over [120,1024]. f32 out.
// ---------------------------------------------------------------------------
__global__ __launch_bounds__(256) void k_lstm(
    const float* __restrict__ gates, const float* __restrict__ bih, const float* __restrict__ bhh,
    float* __restrict__ c, u16* __restrict__ hbf, float* __restrict__ out, int t){
  int gid = blockIdx.x*256 + threadIdx.x;
  int b = gid >> 10, j = gid & 1023;
  const float* g = gates + (size_t)b*G_;
  float si = g[j]      + bih[j]      + bhh[j];
  float sf = g[j+1024] + bih[j+1024] + bhh[j+1024];
  float sg = g[j+2048] + bih[j+2048] + bhh[j+2048];
  float so = g[j+3072] + bih[j+3072] + bhh[j+3072];
  float cn = sigf(sf) * c[gid] + sigf(si) * tanh_fast(sg);
  float hn = sigf(so) * tanh_fast(cn);
  c[gid] = cn; hbf[gid] = f2b(hn);
  out[OUT_HDD + ((size_t)b*T_ + t)*H_ + j] = hn;
}

// ---------------------------------------------------------------------------
extern "C" void kernel_launch(void* const* d_in, const int* in_sizes, int n_in,
                              void* d_out, int out_size, void* d_ws, size_t ws_size,
                              hipStream_t stream){
  (void)in_sizes; (void)n_in; (void)out_size;
  const float* feat = (const float*)d_in[0];
  const float* Whw  = (const float*)d_in[1];
  const float* Whb  = (const float*)d_in[2];
  const float* Wcw  = (const float*)d_in[3];
  const float* Wcb  = (const float*)d_in[4];
  const float* Wxa  = (const float*)d_in[5];
  const float* Wha  = (const float*)d_in[6];
  const float* wa   = (const float*)d_in[7];
  const float* Wb   = (const float*)d_in[8];
  const float* bb   = (const float*)d_in[9];
  const float* Wih  = (const float*)d_in[10];
  const float* Whh  = (const float*)d_in[11];
  const float* bih  = (const float*)d_in[12];
  const float* bhh  = (const float*)d_in[13];
  float* out = (float*)d_out;
  char* ws = (char*)d_ws;
  float* c     = (float*)(ws + WS_C);
  u16*   hbf   = (u16*)  (ws + WS_HBF);
  u16*   vbf   = (u16*)  (ws + WS_VBF);
  u16*   wxaT  = (u16*)  (ws + WS_WXAT);
  u16*   whaT  = (u16*)  (ws + WS_WHAT);
  u16*   wbT   = (u16*)  (ws + WS_WBT);
  float* gates = (float*)(ws + WS_GATES);
  u16*   wihbf = (u16*)  (ws + WS_WIHBF);
  u16*   whhbf = (u16*)  (ws + WS_WHHBF);
  const bool big = ws_size >= WS_BIG_NEED;

  k_pre <<<321, 256, 0, stream>>>(Wxa, Wha, Wb, wxaT, whaT, wbT);
  if(big) k_conv<<<2048, 256, 0, stream>>>(Wih, Whh, wihbf, whhbf);
  k_init<<<120, 256, 0, stream>>>(feat, Whw, Whb, Wcw, Wcb, c, hbf);
  for(int t=0; t<T_; t++){
    k_att <<<120, 256, 0, stream>>>(feat, wxaT, whaT, wbT, wa, bb, hbf, gates, vbf, out, t);
    if(big) k_gemm<true> <<<448, 128, 0, stream>>>(vbf, hbf, wihbf, whhbf, gates);
    else    k_gemm<false><<<448, 128, 0, stream>>>(vbf, hbf, Wih,   Whh,   gates);
    k_lstm<<<480, 256, 0, stream>>>(gates, bih, bhh, c, hbf, out, t);
  }
}

// Round 4
// 1570.717 us; speedup vs baseline: 1.8185x; 1.8185x over previous
//
#include <hip/hip_runtime.h>

// ---- problem dims ----
#define B_ 120
#define T_ 20
#define L_ 144
#define D_ 64
#define H_ 1024
#define A_ 256
#define R_ 9216   // L*D
#define G_ 4096   // 4H

typedef unsigned short u16;
typedef unsigned int   u32;
typedef __bf16 bf16x8 __attribute__((ext_vector_type(8)));
typedef float  f32x4  __attribute__((ext_vector_type(4)));

// d_out element offsets (f32 elements)
#define OUT_VIS 0
#define OUT_HDD 22118400     // 2400*9216
#define OUT_ALP 24576000     // + 2400*1024
#define OUT_BET 24921600     // + 2400*144

// ws byte offsets (total ~122 MB; measured ws_size = 576 MiB via poison-fill WRITE_SIZE)
#define WS_C     0            // 120*1024 f32
#define WS_HBF   491520       // 120*1024 bf16
#define WS_VBF   737280       // 120*9216 bf16
#define WS_WXAT  2949120      // 256*64 bf16
#define WS_WHAT  2981888      // 256*1024 bf16
#define WS_WBT   3506176      // 64*1024 bf16
#define WS_HAP   3637248      // 8*120*320 f32 (ha/beta split-K partials)
#define WS_GP    4866048      // 20*120*4096 f32 (gates split-K partials)
#define WS_WIHBF 44187648     // 4096*9216 bf16
#define WS_WHHBF 119685120    // 4096*1024 bf16
// end 128073728

__device__ inline u16 f2b(float f){ union{float f; u32 i;} v; v.f = f;
  return (u16)((v.i + 0x7FFFu + ((v.i>>16)&1u)) >> 16); }
__device__ inline float sigf(float x){ return 1.0f/(1.0f+__expf(-x)); }
__device__ inline float tanh_fast(float x){ return 1.0f - 2.0f/(__expf(2.0f*x)+1.0f); }

// pack 8 f32 -> 8 bf16 (RNE) and store 16B
__device__ inline void store8(u16* dst, const float* src){
  float4 x = *(const float4*)src, y = *(const float4*)(src+4);
  uint4 o;
  o.x = (u32)f2b(x.x) | ((u32)f2b(x.y)<<16);
  o.y = (u32)f2b(x.z) | ((u32)f2b(x.w)<<16);
  o.z = (u32)f2b(y.x) | ((u32)f2b(y.y)<<16);
  o.w = (u32)f2b(y.z) | ((u32)f2b(y.w)<<16);
  *(uint4*)dst = o;
}
// load 8 f32 -> bf16x8 frag
__device__ inline bf16x8 cvt8(const float* src){
  float4 x = *(const float4*)src, y = *(const float4*)(src+4);
  union{ bf16x8 v; u16 s[8]; } u;
  u.s[0]=f2b(x.x); u.s[1]=f2b(x.y); u.s[2]=f2b(x.z); u.s[3]=f2b(x.w);
  u.s[4]=f2b(y.x); u.s[5]=f2b(y.y); u.s[6]=f2b(y.z); u.s[7]=f2b(y.w);
  return u.v;
}

// ---------------------------------------------------------------------------
// k_pre: blocks 0..255 whaT rows; 256..319 wbT rows; 320 wxaT. f32 -> bf16.
// ---------------------------------------------------------------------------
__global__ __launch_bounds__(256) void k_pre(
    const float* __restrict__ Wxa, const float* __restrict__ Wha, const float* __restrict__ Wb,
    u16* __restrict__ wxaT, u16* __restrict__ whaT, u16* __restrict__ wbT){
  int bx = blockIdx.x, tid = threadIdx.x;
  if(bx < 256){
    int a = bx;
    for(int k = tid; k < H_; k += 256) whaT[a*H_ + k] = f2b(Wha[k*A_ + a]);
  } else if(bx < 320){
    int d = bx - 256;
    for(int k = tid; k < H_; k += 256) wbT[d*H_ + k] = f2b(Wb[k*D_ + d]);
  } else {
    int a = tid;
    for(int k = 0; k < 64; k++) wxaT[a*64 + k] = f2b(Wxa[k*A_ + a]);
  }
}

// ---------------------------------------------------------------------------
// k_conv: W_ih, W_hh f32 -> bf16 in ws.
// ---------------------------------------------------------------------------
__global__ __launch_bounds__(256) void k_conv(
    const float* __restrict__ Wih, const float* __restrict__ Whh,
    u16* __restrict__ wihbf, u16* __restrict__ whhbf){
  const size_t NIH8 = (size_t)G_*R_/8, NHH8 = (size_t)G_*H_/8, TOT = NIH8+NHH8;
  for(size_t i = (size_t)blockIdx.x*256 + threadIdx.x; i < TOT; i += (size_t)gridDim.x*256){
    if(i < NIH8) store8(wihbf + i*8, Wih + i*8);
    else         store8(whhbf + (i-NIH8)*8, Whh + (i-NIH8)*8);
  }
}

// ---------------------------------------------------------------------------
// k_init: 120 blocks. f0 = mean_L feat[b,0]; h0 -> hbf (bf16), c0 -> c (f32).
// ---------------------------------------------------------------------------
__global__ __launch_bounds__(256) void k_init(
    const float* __restrict__ feat, const float* __restrict__ Whw, const float* __restrict__ Whb,
    const float* __restrict__ Wcw, const float* __restrict__ Wcb,
    float* __restrict__ c, u16* __restrict__ hbf){
  int b = blockIdx.x, tid = threadIdx.x;
  __shared__ float fp[4][64];
  __shared__ float f0[64];
  int d = tid & 63, g = tid >> 6;
  const float* xt = feat + (size_t)(b*T_)*R_;
  float acc = 0.f;
  for(int l = g; l < L_; l += 4) acc += xt[l*64 + d];
  fp[g][d] = acc;
  __syncthreads();
  if(tid < 64) f0[tid] = (fp[0][tid]+fp[1][tid]+fp[2][tid]+fp[3][tid]) * (1.0f/L_);
  __syncthreads();
  for(int jj=0; jj<4; jj++){
    int j = tid + jj*256;
    float ah=0.f, ac2=0.f;
    for(int dd=0; dd<64; dd++){
      float fv = f0[dd];
      ah  += fv * Whw[j*64+dd];
      ac2 += fv * Wcw[j*64+dd];
    }
    hbf[b*H_ + j] = f2b(tanh_fast(ah + Whb[j]));
    c[b*H_ + j]   = tanh_fast(ac2 + Wcb[j]);
  }
}

// ---------------------------------------------------------------------------
// k_ha: ha+beta-logit GEMM for ALL b: [120x1024] @ [1024 x 320] (320 = 256 ha
// cols | 64 beta cols). grid 40 = ns(5 n-tiles of 64) x ks(8 K-slices of 128).
// Weights read ONCE per step (0.64 MB) vs 76.8 MB for per-b recompute.
// Partials hap[ks][b][col]; reduced in k_att phase 0.
// ---------------------------------------------------------------------------
__global__ __launch_bounds__(256) void k_ha(
    const u16* __restrict__ hbf, const u16* __restrict__ whaT, const u16* __restrict__ wbT,
    float* __restrict__ hap){
  int bx = blockIdx.x;
  int ns = bx >> 3, ks = bx & 7;
  int tid = threadIdx.x, lane = tid & 63, w = tid >> 6, r = lane & 15, q = lane >> 4;
  __shared__ u16 a_lds[128*136];   // 120(128) rows x 128 k, pad 8
  #pragma unroll
  for(int i=0;i<8;i++){
    int idx = tid + i*256, rw = idx >> 4, cch = idx & 15;
    float4 va = {0.f,0.f,0.f,0.f};
    if(rw < B_) va = *(const float4*)(hbf + (size_t)rw*H_ + ks*128 + cch*8);
    *(float4*)&a_lds[rw*136 + cch*8] = va;
  }
  __syncthreads();
  int col = ns*64 + w*16 + r;
  const u16* brow = (col < 256) ? (whaT + (size_t)col*H_) : (wbT + (size_t)(col-256)*H_);
  f32x4 acc8[8];
  #pragma unroll
  for(int mi=0; mi<8; mi++) acc8[mi] = (f32x4){0.f,0.f,0.f,0.f};
  #pragma unroll
  for(int kb=0; kb<4; kb++){
    bf16x8 bfr = *(const bf16x8*)(brow + ks*128 + kb*32 + q*8);
    #pragma unroll
    for(int mi=0; mi<8; mi++){
      bf16x8 af = *(const bf16x8*)&a_lds[(mi*16+r)*136 + kb*32 + q*8];
      acc8[mi] = __builtin_amdgcn_mfma_f32_16x16x32_bf16(af, bfr, acc8[mi], 0,0,0);
    }
  }
  float* o = hap + (size_t)ks*B_*320;
  #pragma unroll
  for(int mi=0; mi<8; mi++)
    #pragma unroll
    for(int reg=0; reg<4; reg++){
      int m = mi*16 + q*4 + reg;
      if(m < B_) o[(size_t)m*320 + col] = acc8[mi][reg];
    }
}

// ---------------------------------------------------------------------------
// k_att: one block per b (120 x 256).
//  0) reduce hap -> hasm (256 ha cols) + beta (sig of 64 cols + bb)
//  2) scores via MFMA xt@wxaT^T -> tanh(.+ha)*wa, 16-lane reduce -> spart
//  3) softmax over L=144 -> alpha ; 4) v = xt*(1+alpha)*beta -> vis f32 + vbf
// ---------------------------------------------------------------------------
__global__ __launch_bounds__(256) void k_att(
    const float* __restrict__ feat, const u16* __restrict__ wxaT,
    const float* __restrict__ wa, const float* __restrict__ bb,
    const float* __restrict__ hap, u16* __restrict__ vbf,
    float* __restrict__ out, int t){
  int b = blockIdx.x, tid = threadIdx.x;
  int lane = tid & 63, w = tid >> 6, r = lane & 15, q = lane >> 4;
  size_t row = (size_t)b*T_ + t;

  __shared__ float hasm[256];
  __shared__ float wasm[256];
  __shared__ float bsm[64];
  __shared__ float spart[4][160];
  __shared__ float amul[160];

  // ---- phase 0: reduce ha/beta partials ----
  {
    float s = 0.f;
    #pragma unroll
    for(int ks=0; ks<8; ks++) s += hap[((size_t)ks*B_ + b)*320 + tid];
    hasm[tid] = s;
    wasm[tid] = wa[tid];
    if(tid < 64){
      float s2 = bb[tid];
      #pragma unroll
      for(int ks=0; ks<8; ks++) s2 += hap[((size_t)ks*B_ + b)*320 + 256 + tid];
      float bv = sigf(s2);
      bsm[tid] = bv;
      out[OUT_BET + row*D_ + tid] = bv;
    }
  }
  __syncthreads();

  // ---- phase 2: s[l] = sum_a tanh(xa[l,a]+ha[a])*wa[a] ----
  const float* xt = feat + row*R_;
  {
    bf16x8 xb[4][2];
    #pragma unroll
    for(int ni=0; ni<4; ni++){
      int n = w*64 + ni*16 + r;
      xb[ni][0] = *(const bf16x8*)(wxaT + n*64 +  0 + q*8);
      xb[ni][1] = *(const bf16x8*)(wxaT + n*64 + 32 + q*8);
    }
    for(int m=0; m<9; m++){
      bf16x8 a0 = cvt8(xt + (m*16 + r)*64 +  0 + q*8);
      bf16x8 a1 = cvt8(xt + (m*16 + r)*64 + 32 + q*8);
      float ps0=0.f, ps1=0.f, ps2=0.f, ps3=0.f;
      #pragma unroll
      for(int ni=0; ni<4; ni++){
        f32x4 acc = (f32x4){0.f,0.f,0.f,0.f};
        acc = __builtin_amdgcn_mfma_f32_16x16x32_bf16(a0, xb[ni][0], acc, 0,0,0);
        acc = __builtin_amdgcn_mfma_f32_16x16x32_bf16(a1, xb[ni][1], acc, 0,0,0);
        int col = w*64 + ni*16 + r;
        float ha = hasm[col], wv = wasm[col];
        ps0 += tanh_fast(acc[0] + ha) * wv;
        ps1 += tanh_fast(acc[1] + ha) * wv;
        ps2 += tanh_fast(acc[2] + ha) * wv;
        ps3 += tanh_fast(acc[3] + ha) * wv;
      }
      float ps[4] = {ps0, ps1, ps2, ps3};
      #pragma unroll
      for(int reg=0; reg<4; reg++){
        float v = ps[reg];
        v += __shfl_xor(v, 1); v += __shfl_xor(v, 2);
        v += __shfl_xor(v, 4); v += __shfl_xor(v, 8);
        if(r == 0) spart[w][m*16 + q*4 + reg] = v;
      }
    }
  }
  __syncthreads();

  // ---- phase 3: softmax over L=144 (wave 0) ----
  if(tid < 64){
    float v0 = spart[0][tid]    + spart[1][tid]    + spart[2][tid]    + spart[3][tid];
    float v1 = spart[0][tid+64] + spart[1][tid+64] + spart[2][tid+64] + spart[3][tid+64];
    float v2 = -1e30f;
    if(tid < 16)
      v2 = spart[0][tid+128] + spart[1][tid+128] + spart[2][tid+128] + spart[3][tid+128];
    float m = fmaxf(fmaxf(v0, v1), v2);
    #pragma unroll
    for(int off=32; off; off>>=1) m = fmaxf(m, __shfl_xor(m, off));
    float e0 = __expf(v0-m), e1 = __expf(v1-m);
    float e2 = (tid < 16) ? __expf(v2-m) : 0.0f;
    float s = (e0+e1)+e2;
    #pragma unroll
    for(int off=32; off; off>>=1) s += __shfl_xor(s, off);
    float inv = 1.0f/s;
    float al0 = e0*inv, al1 = e1*inv;
    amul[tid] = 1.0f+al0; amul[tid+64] = 1.0f+al1;
    out[OUT_ALP + row*L_ + tid]    = al0;
    out[OUT_ALP + row*L_ + tid+64] = al1;
    if(tid < 16){
      float al2 = e2*inv;
      amul[tid+128] = 1.0f+al2;
      out[OUT_ALP + row*L_ + tid+128] = al2;
    }
  }
  __syncthreads();

  // ---- phase 4: v = xt*(1+alpha)*beta -> vis f32 + vbf bf16 ----
  float* vout = out + OUT_VIS + row*R_;
  u16* vb = vbf + (size_t)b*R_;
  for(int i = tid; i < R_/4; i += 256){
    int e = i*4;
    int l = e >> 6, d = e & 63;
    float4 x = *(const float4*)(xt + e);
    float m1 = amul[l];
    float4 o4;
    o4.x = x.x*m1*bsm[d];   o4.y = x.y*m1*bsm[d+1];
    o4.z = x.z*m1*bsm[d+2]; o4.w = x.w*m1*bsm[d+3];
    *(float4*)(vout + e) = o4;
    uint2 p;
    p.x = (u32)f2b(o4.x) | ((u32)f2b(o4.y)<<16);
    p.y = (u32)f2b(o4.z) | ((u32)f2b(o4.w)<<16);
    *(uint2*)(vb + e) = p;
  }
}

// ---------------------------------------------------------------------------
// k_gemm: gates split-K GEMM. K = 10240 (9216 vbf@Wih + 1024 hbf@Whh) in 20
// uniform slices of 512 (ks 0..17 -> Wih, 18..19 -> Whh). grid 640 = ks(20) x
// nt(32, N=128). Block 256 thr = 4 waves (2x2), tile 128M x 128N. Partials to
// gp[ks][b][col] (no atomics); reduced in k_lstm.
// ---------------------------------------------------------------------------
__global__ __launch_bounds__(256) void k_gemm(
    const u16* __restrict__ vbf, const u16* __restrict__ hbf,
    const u16* __restrict__ wihbf, const u16* __restrict__ whhbf,
    float* __restrict__ gp){
  int bx = blockIdx.x;
  int ks = bx >> 5;
  int j0 = (bx & 31) * 128;
  int tid = threadIdx.x;
  int lane = tid & 63, w = tid >> 6;
  int wm = w & 1, wn = w >> 1;
  int r = lane & 15, q = lane >> 4;
  const bool hh = (ks >= 18);
  const u16* Asrc = hh ? hbf : vbf;
  const u16* Bsrc = hh ? whhbf : wihbf;
  const int  str  = hh ? H_ : R_;
  const int  koff = hh ? (ks-18)*512 : ks*512;
  __shared__ u16 a_lds[128*72];
  __shared__ u16 b_lds[128*72];
  f32x4 acc[4][4];
  #pragma unroll
  for(int i=0;i<4;i++)
    #pragma unroll
    for(int j=0;j<4;j++) acc[i][j] = (f32x4){0.f,0.f,0.f,0.f};

  for(int k0 = 0; k0 < 512; k0 += 64){
    __syncthreads();
    #pragma unroll
    for(int i=0;i<4;i++){
      int idx = tid + i*256, rw = idx >> 3, cch = idx & 7;
      float4 va = {0.f,0.f,0.f,0.f};
      if(rw < B_) va = *(const float4*)(Asrc + (size_t)rw*str + koff + k0 + cch*8);
      *(float4*)&a_lds[rw*72 + cch*8] = va;
      *(float4*)&b_lds[rw*72 + cch*8] =
          *(const float4*)(Bsrc + (size_t)(j0+rw)*str + koff + k0 + cch*8);
    }
    __syncthreads();
    #pragma unroll
    for(int kb=0; kb<2; kb++){
      bf16x8 af[4], bfr[4];
      #pragma unroll
      for(int mi=0; mi<4; mi++) af[mi]  = *(const bf16x8*)&a_lds[(wm*64+mi*16+r)*72 + kb*32 + q*8];
      #pragma unroll
      for(int ni=0; ni<4; ni++) bfr[ni] = *(const bf16x8*)&b_lds[(wn*64+ni*16+r)*72 + kb*32 + q*8];
      #pragma unroll
      for(int mi=0; mi<4; mi++)
        #pragma unroll
        for(int ni=0; ni<4; ni++)
          acc[mi][ni] = __builtin_amdgcn_mfma_f32_16x16x32_bf16(af[mi], bfr[ni], acc[mi][ni], 0,0,0);
    }
  }
  float* o = gp + (size_t)ks*B_*G_;
  #pragma unroll
  for(int mi=0; mi<4; mi++)
    #pragma unroll
    for(int ni=0; ni<4; ni++)
      #pragma unroll
      for(int reg=0; reg<4; reg++){
        int m = wm*64 + mi*16 + q*4 + reg;
        if(m < B_) o[(size_t)m*G_ + j0 + wn*64 + ni*16 + r] = acc[mi][ni][reg];
      }
}

// ---------------------------------------------------------------------------
// k_lstm: 480 blocks x 256 — reduce 20 gate partials + biases, pointwise LSTM.
// ---------------------------------------------------------------------------
__global__ __launch_bounds__(256) void k_lstm(
    const float* __restrict__ gp, const float* __restrict__ bih, const float* __restrict__ bhh,
    float* __restrict__ c, u16* __restrict__ hbf, float* __restrict__ out, int t){
  int gid = blockIdx.x*256 + threadIdx.x;
  int b = gid >> 10, j = gid & 1023;
  float si = bih[j]      + bhh[j];
  float sf = bih[j+1024] + bhh[j+1024];
  float sg = bih[j+2048] + bhh[j+2048];
  float so = bih[j+3072] + bhh[j+3072];
  #pragma unroll
  for(int ks=0; ks<20; ks++){
    const float* g = gp + ((size_t)(ks*B_ + b))*G_;
    si += g[j]; sf += g[j+1024]; sg += g[j+2048]; so += g[j+3072];
  }
  float cn = sigf(sf) * c[gid] + sigf(si) * tanh_fast(sg);
  float hn = sigf(so) * tanh_fast(cn);
  c[gid] = cn; hbf[gid] = f2b(hn);
  out[OUT_HDD + ((size_t)b*T_ + t)*H_ + j] = hn;
}

// ---------------------------------------------------------------------------
extern "C" void kernel_launch(void* const* d_in, const int* in_sizes, int n_in,
                              void* d_out, int out_size, void* d_ws, size_t ws_size,
                              hipStream_t stream){
  (void)in_sizes; (void)n_in; (void)out_size; (void)ws_size;
  const float* feat = (const float*)d_in[0];
  const float* Whw  = (const float*)d_in[1];
  const float* Whb  = (const float*)d_in[2];
  const float* Wcw  = (const float*)d_in[3];
  const float* Wcb  = (const float*)d_in[4];
  const float* Wxa  = (const float*)d_in[5];
  const float* Wha  = (const float*)d_in[6];
  const float* wa   = (const float*)d_in[7];
  const float* Wb   = (const float*)d_in[8];
  const float* bb   = (const float*)d_in[9];
  const float* Wih  = (const float*)d_in[10];
  const float* Whh  = (const float*)d_in[11];
  const float* bih  = (const float*)d_in[12];
  const float* bhh  = (const float*)d_in[13];
  float* out = (float*)d_out;
  char* ws = (char*)d_ws;
  float* c     = (float*)(ws + WS_C);
  u16*   hbf   = (u16*)  (ws + WS_HBF);
  u16*   vbf   = (u16*)  (ws + WS_VBF);
  u16*   wxaT  = (u16*)  (ws + WS_WXAT);
  u16*   whaT  = (u16*)  (ws + WS_WHAT);
  u16*   wbT   = (u16*)  (ws + WS_WBT);
  float* hap   = (float*)(ws + WS_HAP);
  float* gp    = (float*)(ws + WS_GP);
  u16*   wihbf = (u16*)  (ws + WS_WIHBF);
  u16*   whhbf = (u16*)  (ws + WS_WHHBF);

  k_pre <<<321,  256, 0, stream>>>(Wxa, Wha, Wb, wxaT, whaT, wbT);
  k_conv<<<2048, 256, 0, stream>>>(Wih, Whh, wihbf, whhbf);
  k_init<<<120,  256, 0, stream>>>(feat, Whw, Whb, Wcw, Wcb, c, hbf);
  k_ha  <<<40,   256, 0, stream>>>(hbf, whaT, wbT, hap);
  for(int t=0; t<T_; t++){
    k_att <<<120, 256, 0, stream>>>(feat, wxaT, wa, bb, hap, vbf, out, t);
    k_gemm<<<640, 256, 0, stream>>>(vbf, hbf, wihbf, whhbf, gp);
    k_lstm<<<480, 256, 0, stream>>>(gp, bih, bhh, c, hbf, out, t);
    if(t < T_-1) k_ha<<<40, 256, 0, stream>>>(hbf, whaT, wbT, hap);
  }
}